// Round 8
// baseline (713.961 us; speedup 1.0000x reference)
//
#include <hip/hip_runtime.h>
#include <hip/hip_bf16.h>

// Problem constants (from reference)
#define N_DIM   128   // NODE_DIM
#define MUL0    128
#define MUL1    64
#define MUL2    32
#define NIRR    224   // NUM_IRREPS
#define SPHD    480   // SPH_DIM
#define HID     352   // HIDDEN
#define NBASIS  20
#define EPSV    1e-5f

typedef __attribute__((ext_vector_type(8))) short bf16x8;
typedef __attribute__((ext_vector_type(4))) float f32x4;

__device__ __forceinline__ float wave_sum(float v) {
  #pragma unroll
  for (int o = 32; o > 0; o >>= 1) v += __shfl_xor(v, o, 64);
  return v;
}

__device__ __forceinline__ unsigned short f2bf(float f) {
  unsigned int u = __float_as_uint(f);
  u = (u + 0x7fff + ((u >> 16) & 1)) >> 16;  // RNE
  return (unsigned short)u;
}

__device__ __forceinline__ float bf2f(unsigned short v) {
  return __uint_as_float(((unsigned int)v) << 16);
}

// packed RNE f32->bf16 pair (lo = a, hi = b)
__device__ __forceinline__ unsigned int cvt_pk_bf16(float a, float b) {
  unsigned int r;
  asm("v_cvt_pk_bf16_f32 %0, %1, %2" : "=v"(r) : "v"(a), "v"(b));
  return r;
}

// ---------------------------------------------------------------------------
// Kernel 1: per-node LayerNorm (scalar) + O3 layer norm (spherical).
// ---------------------------------------------------------------------------
__global__ __launch_bounds__(256) void node_norm_kernel(
    const float* __restrict__ x_scalar, const float* __restrict__ x_sph,
    const float* __restrict__ ln_g, const float* __restrict__ ln_b,
    const float* __restrict__ o3_w, const float* __restrict__ o3_b,
    float* __restrict__ out_scal, float* __restrict__ out_sph, int n_nodes) {
  const int n = blockIdx.x * 4 + (threadIdx.x >> 6);
  if (n >= n_nodes) return;
  const int l = threadIdx.x & 63;

  const float* xs = x_scalar + (size_t)n * N_DIM;
  float a0 = xs[l], a1 = xs[l + 64];
  float mu = wave_sum(a0 + a1) * (1.f / 128.f);
  float d0 = a0 - mu, d1 = a1 - mu;
  float var = wave_sum(d0 * d0 + d1 * d1) * (1.f / 128.f);
  float sc = rsqrtf(var + EPSV);
  float* os = out_scal + (size_t)n * N_DIM;
  os[l]      = d0 * sc * ln_g[l]      + ln_b[l];
  os[l + 64] = d1 * sc * ln_g[l + 64] + ln_b[l + 64];

  const float* xp = x_sph + (size_t)n * SPHD;
  float s0 = xp[l], s1 = xp[l + 64];
  mu = wave_sum(s0 + s1) * (1.f / 128.f);
  d0 = s0 - mu; d1 = s1 - mu;
  var = wave_sum(d0 * d0 + d1 * d1) * (1.f / 128.f);
  sc = rsqrtf(var + EPSV);
  float* op = out_sph + (size_t)n * SPHD;
  op[l]      = d0 * sc * o3_w[l]      + o3_b[l];
  op[l + 64] = d1 * sc * o3_w[l + 64] + o3_b[l + 64];

  float v0 = xp[128 + l], v1 = xp[128 + 64 + l], v2 = xp[128 + 128 + l];
  float nv = wave_sum(v0 * v0 + v1 * v1 + v2 * v2) * (1.f / 192.f);
  sc = rsqrtf(nv + EPSV);
  op[128 + l]       = v0 * sc * o3_w[MUL0 + (l) / 3];
  op[128 + 64 + l]  = v1 * sc * o3_w[MUL0 + (l + 64) / 3];
  op[128 + 128 + l] = v2 * sc * o3_w[MUL0 + (l + 128) / 3];

  float t0 = xp[320 + l], t1 = xp[320 + 64 + l];
  float t2 = (l < 32) ? xp[320 + 128 + l] : 0.f;
  float nt = wave_sum(t0 * t0 + t1 * t1 + t2 * t2) * (1.f / 160.f);
  sc = rsqrtf(nt + EPSV);
  op[320 + l]      = t0 * sc * o3_w[MUL0 + MUL1 + (l) / 5];
  op[320 + 64 + l] = t1 * sc * o3_w[MUL0 + MUL1 + (l + 64) / 5];
  if (l < 32) op[320 + 128 + l] = t2 * sc * o3_w[MUL0 + MUL1 + (l + 128) / 5];
}

// ---------------------------------------------------------------------------
// Pack B (KxN fp32, K=128) into bf16 MFMA-fragment order.
// ---------------------------------------------------------------------------
__global__ void pack_b_kernel(const float* __restrict__ B, unsigned short* __restrict__ Bp,
                              int N, int NT) {
  int id = blockIdx.x * 256 + threadIdx.x;
  int total = 4 * NT * 64;
  if (id >= total) return;
  int lane = id & 63;
  int tmp = id >> 6;
  int nt = tmp % NT, ks = tmp / NT;
  int n = nt * 16 + (lane & 15);
  int kb = ks * 32 + (lane >> 4) * 8;
  unsigned short* o = Bp + (size_t)id * 8;
  #pragma unroll
  for (int j = 0; j < 8; ++j)
    o[j] = (n < N) ? f2bf(B[(size_t)(kb + j) * N + n]) : (unsigned short)0;
}

// Pack Wrbf [20][352] into MFMA B-fragment order for K=32 (k=20..31 zero),
// NT = 22 col-tiles.
__global__ void pack_bw_kernel(const float* __restrict__ Wrbf, unsigned short* __restrict__ Bpw) {
  int id = blockIdx.x * 256 + threadIdx.x;
  if (id >= 22 * 64) return;
  int lane = id & 63, nt = id >> 6;
  int n = nt * 16 + (lane & 15);
  int kb = (lane >> 4) * 8;
  unsigned short* o = Bpw + (size_t)id * 8;
  #pragma unroll
  for (int j = 0; j < 8; ++j) {
    int k = kb + j;
    o[j] = (k < NBASIS) ? f2bf(Wrbf[(size_t)k * HID + n]) : (unsigned short)0;
  }
}

// ---------------------------------------------------------------------------
// bf16 MFMA GEMM: C = act(A @ B + bias), K = 128 fixed.
// PERM: store columns permuted for the gather's paired-load layout:
//   col <  96       -> slot 2*col       (pairs with col+256)
//   96 <= col < 256 -> slot col + 96
//   col >= 256      -> slot 2*(col-256)+1
// ---------------------------------------------------------------------------
template <bool A_BF16, bool SILU, bool OUT_BF16, bool PERM>
__global__ __launch_bounds__(256) void mfma_gemm_kernel(
    const void* __restrict__ Ap, const unsigned short* __restrict__ Bp,
    const float* __restrict__ bias, void* __restrict__ Cp,
    int M, int N, int NT) {
  const int lane = threadIdx.x & 63;
  const int wave = threadIdx.x >> 6;
  const int bm = blockIdx.x * 64 + wave * 16;
  const int bn = blockIdx.y * 64;
  const int q = lane >> 4;
  const int arow = min(bm + (lane & 15), M - 1);  // clamp: OOB rows give garbage, stores guarded

  f32x4 acc[4] = {};
  #pragma unroll
  for (int ks = 0; ks < 4; ++ks) {
    const int k = ks * 32 + q * 8;
    bf16x8 a;
    if (A_BF16) {
      a = *(const bf16x8*)((const unsigned short*)Ap + (size_t)arow * 128 + k);
    } else {
      const float* ap = (const float*)Ap + (size_t)arow * 128 + k;
      float4 f0 = *(const float4*)ap;
      float4 f1 = *(const float4*)(ap + 4);
      union { bf16x8 v; unsigned short s[8]; } cv;
      cv.s[0] = f2bf(f0.x); cv.s[1] = f2bf(f0.y); cv.s[2] = f2bf(f0.z); cv.s[3] = f2bf(f0.w);
      cv.s[4] = f2bf(f1.x); cv.s[5] = f2bf(f1.y); cv.s[6] = f2bf(f1.z); cv.s[7] = f2bf(f1.w);
      a = cv.v;
    }
    #pragma unroll
    for (int nt = 0; nt < 4; ++nt) {
      bf16x8 b = *(const bf16x8*)(Bp + ((size_t)(ks * NT + blockIdx.y * 4 + nt) * 64 + lane) * 8);
      acc[nt] = __builtin_amdgcn_mfma_f32_16x16x32_bf16(a, b, acc[nt], 0, 0, 0);
    }
  }
  #pragma unroll
  for (int nt = 0; nt < 4; ++nt) {
    int col = bn + nt * 16 + (lane & 15);
    if (col >= N) continue;
    float bz = bias[col];
    int pcol = col;
    if (PERM) pcol = (col < 96) ? (2 * col) : ((col < 256) ? (col + 96) : (2 * (col - 256) + 1));
    #pragma unroll
    for (int i = 0; i < 4; ++i) {
      int r = bm + q * 4 + i;
      if (r >= M) continue;
      float v = acc[nt][i] + bz;
      if (SILU) v = v / (1.f + __expf(-v));
      if (OUT_BF16) ((unsigned short*)Cp)[(size_t)r * N + pcol] = f2bf(v);
      else          ((float*)Cp)[(size_t)r * N + pcol] = v;
    }
  }
}

// ---------------------------------------------------------------------------
// CSR build: histogram, hierarchical exclusive scan (3 kernels), fused fill.
// ---------------------------------------------------------------------------
__global__ void hist_kernel(const int* __restrict__ ei, int* __restrict__ deg, int n_edges) {
  int e = blockIdx.x * blockDim.x + threadIdx.x;
  if (e < n_edges) atomicAdd(&deg[ei[e]], 1);
}

__global__ __launch_bounds__(1024) void scan_part_kernel(
    const int* __restrict__ deg, int* __restrict__ offs, int* __restrict__ bsum, int n) {
  __shared__ int wsum[16];
  const int tid = threadIdx.x, lane = tid & 63, wid = tid >> 6;
  int i = blockIdx.x * 1024 + tid;
  int v = (i < n) ? deg[i] : 0;
  int s = v;
  #pragma unroll
  for (int o = 1; o < 64; o <<= 1) {
    int t = __shfl_up(s, o, 64);
    if (lane >= o) s += t;
  }
  if (lane == 63) wsum[wid] = s;
  __syncthreads();
  if (wid == 0) {
    int ws = (lane < 16) ? wsum[lane] : 0;
    #pragma unroll
    for (int o = 1; o < 16; o <<= 1) {
      int t = __shfl_up(ws, o, 64);
      if (lane >= o) ws += t;
    }
    if (lane < 16) wsum[lane] = ws;
  }
  __syncthreads();
  int excl = ((wid == 0) ? 0 : wsum[wid - 1]) + s - v;
  if (i < n) offs[i] = excl;
  if (tid == 1023) bsum[blockIdx.x] = wsum[15];
}

__global__ __launch_bounds__(64) void scan_tops_kernel(
    const int* __restrict__ bsum, int* __restrict__ bbase, int* __restrict__ offs,
    int nb, int n) {
  const int lane = threadIdx.x;
  int v = (lane < nb) ? bsum[lane] : 0;
  int s = v;
  #pragma unroll
  for (int o = 1; o < 64; o <<= 1) {
    int t = __shfl_up(s, o, 64);
    if (lane >= o) s += t;
  }
  if (lane < nb) bbase[lane] = s - v;
  if (lane == 63) offs[n] = s;  // grand total
}

__global__ __launch_bounds__(1024) void scan_add_kernel(
    int* __restrict__ offs, const int* __restrict__ bbase, int n) {
  int i = blockIdx.x * 1024 + threadIdx.x;
  if (i < n) offs[i] += bbase[blockIdx.x];
}

// Fused fill + pre-gather: place each edge's rbf/vec/src directly at its CSR
// slot. Reads coalesced (edge-order), writes scattered.
__global__ void fill_kernel(const int* __restrict__ ei, const int* __restrict__ offs,
                            int* __restrict__ cursor, const int* __restrict__ edge_src,
                            const float* __restrict__ rbf, const float* __restrict__ vec,
                            float* __restrict__ rbf_s, float* __restrict__ vec_s,
                            int* __restrict__ src_s, int n_edges) {
  int e = blockIdx.x * blockDim.x + threadIdx.x;
  if (e < n_edges) {
    int d = ei[e];
    int p = atomicAdd(&cursor[d], 1);
    int ii = offs[d] + p;
    src_s[ii] = edge_src[e];
    const float4* rp = (const float4*)(rbf + (size_t)e * NBASIS);
    float4* op = (float4*)(rbf_s + (size_t)ii * NBASIS);
    op[0] = rp[0]; op[1] = rp[1]; op[2] = rp[2]; op[3] = rp[3]; op[4] = rp[4];
    vec_s[(size_t)ii * 3]     = vec[(size_t)e * 3];
    vec_s[(size_t)ii * 3 + 1] = vec[(size_t)e * 3 + 1];
    vec_s[(size_t)ii * 3 + 2] = vec[(size_t)e * 3 + 2];
  }
}

// ---------------------------------------------------------------------------
// Gather kernel v8: MFMA-fused filter weights + depth-8 so prefetch.
// R7 post-mortem: VALUBusy 28%, MFMA 2%, HBM 16% -> ~70% stall. Block critical
// path dominated by the accumulate's serial so_load chain (2 in flight,
// ~12 rounds x ~400cy). Fix: per node, process edges in groups of <=8 with all
// 8 random so-dword loads issued before any accumulation (guards are
// block-uniform -> no divergence). Rounds per node: ceil(deg/2)->ceil(deg/8).
// Accumulation order unchanged (ascending il) -> bit-identical to R7.
// ---------------------------------------------------------------------------
#define NPB 3
#define CHUNK 32
#define FWPAD 36   // LDS row pad: 72B stride => 8B-aligned b64 writes, spread banks
#define GRP 8
#define S3f  1.7320508075688772f
#define S15f 3.872983346207417f
#define S5f  2.2360679774997896f

__device__ __forceinline__ void so_load(const unsigned short* __restrict__ so,
                                        int src, int t, bool hasB,
                                        float& sA, float& sB) {
  const unsigned short* p = so + (size_t)src * HID;
  if (hasB) {
    unsigned int u = *(const unsigned int*)(p + 2 * t);
    sA = __uint_as_float(u << 16);
    sB = __uint_as_float(u & 0xffff0000u);
  } else {
    sA = bf2f(p[t + 96]);
    sB = 0.f;
  }
}

__global__ __launch_bounds__(256) void gather_kernel(
    const float* __restrict__ rbf_s, const float* __restrict__ vec_s,
    const unsigned short* __restrict__ Bpw, const unsigned short* __restrict__ so,
    const int* __restrict__ src_s, const int* __restrict__ offs,
    float* __restrict__ out_scal, float* __restrict__ out_sph, int n_nodes) {
  __shared__ float rbf_l[CHUNK * NBASIS];        // 2560 B (rows 80B, 16B-aligned)
  __shared__ float sh_l[CHUNK * 8];              // 1024 B
  __shared__ int   src_l[CHUNK];                 // 128 B
  __shared__ unsigned short fw_l[HID * FWPAD];   // 25344 B, [col][edge] transposed

  const int t = threadIdx.x;
  const int lane = t & 63, w = t >> 6, q = lane >> 4;
  const bool hasB = (t < 96);

  const int n0 = blockIdx.x * NPB;
  if (n0 >= n_nodes) return;
  const int nE = min(n0 + NPB, n_nodes);
  const int E0 = offs[n0], E1 = offs[nE];

  int eb0[NPB], eb1[NPB];
  #pragma unroll
  for (int i = 0; i < NPB; ++i) {
    int nd = n0 + i;
    eb0[i] = (nd < n_nodes) ? offs[nd] : E1;
    eb1[i] = (nd < n_nodes) ? offs[nd + 1] : E1;
  }

  float a0[NPB] = {}, a1[NPB] = {}, a2[NPB] = {}, a3[NPB] = {}, a4[NPB] = {}, aB[NPB] = {};

  for (int C0 = E0; C0 < E1; C0 += CHUNK) {
    const int C1 = min(C0 + CHUNK, E1);
    const int ns = C1 - C0;

    // ---- stage chunk (coalesced; CSR range contiguous) ----
    for (int i = t; i < ns * NBASIS; i += 256)
      rbf_l[i] = rbf_s[(size_t)C0 * NBASIS + i];
    if (t < ns) {
      const int ii = C0 + t;
      src_l[t] = src_s[ii];
      float vx = vec_s[3 * (size_t)ii], vy = vec_s[3 * (size_t)ii + 1], vz = vec_s[3 * (size_t)ii + 2];
      float rn = rsqrtf(vx * vx + vy * vy + vz * vz);
      float x = vx * rn, y = vy * rn, z = vz * rn;
      float* sp = &sh_l[t * 8];
      sp[0] = S3f * x; sp[1] = S3f * y; sp[2] = S3f * z;
      sp[3] = S15f * x * z;
      sp[4] = S15f * x * y;
      sp[5] = S5f * (y * y - 0.5f * (x * x + z * z));
      sp[6] = S15f * y * z;
      sp[7] = 0.5f * S15f * (z * z - x * x);
    }
    __syncthreads();

    // ---- MFMA: fw[0..31][0..351] = rbf_chunk @ Wrbf, into LDS ----
    {
      const int et = w >> 1;
      const int ntb = (w & 1) * 11;
      const int mrow = et * 16 + (lane & 15);
      const float* ar = &rbf_l[mrow * NBASIS];
      f32x4 lo = {}, hi = {};
      if (q < 2) {
        lo = *(const f32x4*)(ar + q * 8);
        hi = *(const f32x4*)(ar + q * 8 + 4);
      } else if (q == 2) {
        lo = *(const f32x4*)(ar + 16);  // k=16..19; k>=20 zero-padded
      }
      union { bf16x8 v; unsigned int u[4]; } af;
      af.u[0] = cvt_pk_bf16(lo[0], lo[1]);
      af.u[1] = cvt_pk_bf16(lo[2], lo[3]);
      af.u[2] = cvt_pk_bf16(hi[0], hi[1]);
      af.u[3] = cvt_pk_bf16(hi[2], hi[3]);
      #pragma unroll
      for (int j = 0; j < 11; ++j) {
        const int nt = ntb + j;
        bf16x8 b = *(const bf16x8*)(Bpw + (size_t)(nt * 64 + lane) * 8);
        f32x4 acc = {};
        acc = __builtin_amdgcn_mfma_f32_16x16x32_bf16(af.v, b, acc, 0, 0, 0);
        const int col = nt * 16 + (lane & 15);
        uint2 pk;
        pk.x = cvt_pk_bf16(acc[0], acc[1]);
        pk.y = cvt_pk_bf16(acc[2], acc[3]);
        *(uint2*)&fw_l[col * FWPAD + et * 16 + q * 4] = pk;
      }
    }
    __syncthreads();

    // ---- accumulate: per-node groups of <=8, all loads issued first ----
    auto edge = [&](int il, float sA, float sB, float fwA, float fwB, int nn) {
      float fA = sA * fwA;
      if (t < 128) {
        a0[nn] += fA;
      } else if (t < 224) {
        const float* sp = &sh_l[il * 8];
        if (t < 192) {
          a0[nn] += fA * sp[0]; a1[nn] += fA * sp[1]; a2[nn] += fA * sp[2];
        } else {
          a0[nn] += fA * sp[3]; a1[nn] += fA * sp[4]; a2[nn] += fA * sp[5];
          a3[nn] += fA * sp[6]; a4[nn] += fA * sp[7];
        }
      } else {
        a0[nn] += fA;
      }
      if (hasB) aB[nn] += sB * fwB;
    };

    #pragma unroll
    for (int nn = 0; nn < NPB; ++nn) {
      const int lo = max(eb0[nn], C0);
      const int hi = min(eb1[nn], C1);
      for (int base = lo; base < hi; base += GRP) {
        const int cnt = min(hi - base, GRP);   // block-uniform
        float sA[GRP], sB[GRP];
        // phase 1: issue all random so-loads (up to 8 in flight)
        #pragma unroll
        for (int g = 0; g < GRP; ++g) {
          if (g < cnt) {
            const int il = base - C0 + g;
            so_load(so, src_l[il], t, hasB, sA[g], sB[g]);
          }
        }
        // phase 2: accumulate in ascending il order (same order as before)
        #pragma unroll
        for (int g = 0; g < GRP; ++g) {
          if (g < cnt) {
            const int il = base - C0 + g;
            float fwA = bf2f(fw_l[t * FWPAD + il]);
            float fwB = hasB ? bf2f(fw_l[(256 + t) * FWPAD + il]) : 0.f;
            edge(il, sA[g], sB[g], fwA, fwB, nn);
          }
        }
      }
    }
    __syncthreads();
  }

  // ---- flush (base values already in d_out from node_norm) ----
  #pragma unroll
  for (int nn = 0; nn < NPB; ++nn) {
    const int node = n0 + nn;
    if (node >= n_nodes) break;
    float* sph = out_sph + (size_t)node * SPHD;
    float* scl = out_scal + (size_t)node * N_DIM;
    if (t < 128) {
      sph[t] += a0[nn];
    } else if (t < 192) {
      float* p = sph + 128 + 3 * (t - 128);
      p[0] += a0[nn]; p[1] += a1[nn]; p[2] += a2[nn];
    } else if (t < 224) {
      float* p = sph + 320 + 5 * (t - 192);
      p[0] += a0[nn]; p[1] += a1[nn]; p[2] += a2[nn]; p[3] += a3[nn]; p[4] += a4[nn];
    } else {
      scl[t - 224] += a0[nn];
    }
    if (hasB) scl[t + 32] += aB[nn];
  }
}

// ---------------------------------------------------------------------------
extern "C" void kernel_launch(void* const* d_in, const int* in_sizes, int n_in,
                              void* d_out, int out_size, void* d_ws, size_t ws_size,
                              hipStream_t stream) {
  const float* x_scalar = (const float*)d_in[0];
  const float* x_sph    = (const float*)d_in[1];
  const float* rbf      = (const float*)d_in[2];
  const float* vec      = (const float*)d_in[3];
  const float* W1       = (const float*)d_in[4];
  const float* b1       = (const float*)d_in[5];
  const float* W2       = (const float*)d_in[6];
  const float* b2       = (const float*)d_in[7];
  const float* Wrbf     = (const float*)d_in[8];
  const float* ln_g     = (const float*)d_in[9];
  const float* ln_b     = (const float*)d_in[10];
  const float* o3_w     = (const float*)d_in[11];
  const float* o3_b     = (const float*)d_in[12];
  const int*   edge_idx = (const int*)d_in[13];

  const int n_nodes = in_sizes[0] / N_DIM;   // 50000
  const int n_edges = in_sizes[2] / NBASIS;  // 400000

  float* out_scal = (float*)d_out;                       // [n_nodes,128]
  float* out_sph  = out_scal + (size_t)n_nodes * N_DIM;  // [n_nodes,480]

  // workspace layout (16B alignment preserved chunk to chunk)
  float* rbf_s = (float*)d_ws;                                // [n_edges,20] CSR order
  float* vec_s = rbf_s + (size_t)n_edges * NBASIS;            // [n_edges,3]  CSR order
  int*   src_s = (int*)(vec_s + (size_t)n_edges * 3);         // [n_edges]    CSR order
  unsigned short* so_bf = (unsigned short*)(src_s + n_edges); // [n_nodes,352] bf16 permuted
  unsigned short* h_bf  = so_bf + (size_t)n_nodes * HID;      // [n_nodes,128] bf16
  unsigned short* bp1   = h_bf + (size_t)n_nodes * N_DIM;     // 16384 ush
  unsigned short* bp2   = bp1 + 16384;                        // 49152 ush
  unsigned short* bpw   = bp2 + 49152;                        // 22*64*8 = 11264 ush
  int* deg    = (int*)(bpw + 11264);
  int* cursor = deg + n_nodes;
  int* offs   = cursor + n_nodes;       // [n_nodes+1]
  int* bsum   = offs + n_nodes + 1;     // [64]
  int* bbase  = bsum + 64;              // [64]

  const int* edge_dst = edge_idx;
  const int* edge_src = edge_idx + n_edges;

  // 1) node norms -> d_out (scatter base)
  node_norm_kernel<<<(n_nodes + 3) / 4, 256, 0, stream>>>(
      x_scalar, x_sph, ln_g, ln_b, o3_w, o3_b, out_scal, out_sph, n_nodes);

  // 2) pack W1/W2 (MFMA fragment order) + Wrbf (K=32 fragment order)
  pack_b_kernel<<<8, 256, 0, stream>>>(W1, bp1, N_DIM, 8);
  pack_b_kernel<<<24, 256, 0, stream>>>(W2, bp2, HID, 24);
  pack_bw_kernel<<<6, 256, 0, stream>>>(Wrbf, bpw);

  // 3) h = silu(scalar_in @ W1 + b1)  (A fp32, out bf16)
  {
    dim3 g((n_nodes + 63) / 64, 2);
    mfma_gemm_kernel<false, true, true, false><<<g, 256, 0, stream>>>(
        out_scal, bp1, b1, h_bf, n_nodes, N_DIM, 8);
  }
  // 4) scalar_out = h @ W2 + b2  (A bf16, out bf16 PERMUTED for paired loads)
  {
    dim3 g((n_nodes + 63) / 64, 6);
    mfma_gemm_kernel<true, false, true, true><<<g, 256, 0, stream>>>(
        h_bf, bp2, b2, so_bf, n_nodes, HID, 24);
  }

  // 5) CSR build (fill fused with pre-gather: streams land in CSR slots)
  hipMemsetAsync(deg, 0, sizeof(int) * 2 * n_nodes, stream);  // deg + cursor
  hist_kernel<<<(n_edges + 255) / 256, 256, 0, stream>>>(edge_dst, deg, n_edges);
  const int nb = (n_nodes + 1023) / 1024;  // 49
  scan_part_kernel<<<nb, 1024, 0, stream>>>(deg, offs, bsum, n_nodes);
  scan_tops_kernel<<<1, 64, 0, stream>>>(bsum, bbase, offs, nb, n_nodes);
  scan_add_kernel<<<nb, 1024, 0, stream>>>(offs, bbase, n_nodes);
  fill_kernel<<<(n_edges + 255) / 256, 256, 0, stream>>>(
      edge_dst, offs, cursor, edge_src, rbf, vec, rbf_s, vec_s, src_s, n_edges);

  // 6) gather with MFMA-fused filter weights + depth-8 prefetch
  gather_kernel<<<(n_nodes + NPB - 1) / NPB, 256, 0, stream>>>(
      rbf_s, vec_s, bpw, so_bf, src_s, offs, out_scal, out_sph, n_nodes);
}

// Round 9
// 639.826 us; speedup vs baseline: 1.1159x; 1.1159x over previous
//
#include <hip/hip_runtime.h>
#include <hip/hip_bf16.h>

// Problem constants (from reference)
#define N_DIM   128   // NODE_DIM
#define MUL0    128
#define MUL1    64
#define MUL2    32
#define NIRR    224   // NUM_IRREPS
#define SPHD    480   // SPH_DIM
#define HID     352   // HIDDEN
#define NBASIS  20
#define EPSV    1e-5f

typedef __attribute__((ext_vector_type(8))) short bf16x8;
typedef __attribute__((ext_vector_type(4))) float f32x4;

__device__ __forceinline__ float wave_sum(float v) {
  #pragma unroll
  for (int o = 32; o > 0; o >>= 1) v += __shfl_xor(v, o, 64);
  return v;
}

__device__ __forceinline__ unsigned short f2bf(float f) {
  unsigned int u = __float_as_uint(f);
  u = (u + 0x7fff + ((u >> 16) & 1)) >> 16;  // RNE
  return (unsigned short)u;
}

__device__ __forceinline__ float bf2f(unsigned short v) {
  return __uint_as_float(((unsigned int)v) << 16);
}

// packed RNE f32->bf16 pair (lo = a, hi = b)
__device__ __forceinline__ unsigned int cvt_pk_bf16(float a, float b) {
  unsigned int r;
  asm("v_cvt_pk_bf16_f32 %0, %1, %2" : "=v"(r) : "v"(a), "v"(b));
  return r;
}

// ---------------------------------------------------------------------------
// Kernel 1: per-node LayerNorm (scalar) + O3 layer norm (spherical).
// ---------------------------------------------------------------------------
__global__ __launch_bounds__(256) void node_norm_kernel(
    const float* __restrict__ x_scalar, const float* __restrict__ x_sph,
    const float* __restrict__ ln_g, const float* __restrict__ ln_b,
    const float* __restrict__ o3_w, const float* __restrict__ o3_b,
    float* __restrict__ out_scal, float* __restrict__ out_sph, int n_nodes) {
  const int n = blockIdx.x * 4 + (threadIdx.x >> 6);
  if (n >= n_nodes) return;
  const int l = threadIdx.x & 63;

  const float* xs = x_scalar + (size_t)n * N_DIM;
  float a0 = xs[l], a1 = xs[l + 64];
  float mu = wave_sum(a0 + a1) * (1.f / 128.f);
  float d0 = a0 - mu, d1 = a1 - mu;
  float var = wave_sum(d0 * d0 + d1 * d1) * (1.f / 128.f);
  float sc = rsqrtf(var + EPSV);
  float* os = out_scal + (size_t)n * N_DIM;
  os[l]      = d0 * sc * ln_g[l]      + ln_b[l];
  os[l + 64] = d1 * sc * ln_g[l + 64] + ln_b[l + 64];

  const float* xp = x_sph + (size_t)n * SPHD;
  float s0 = xp[l], s1 = xp[l + 64];
  mu = wave_sum(s0 + s1) * (1.f / 128.f);
  d0 = s0 - mu; d1 = s1 - mu;
  var = wave_sum(d0 * d0 + d1 * d1) * (1.f / 128.f);
  sc = rsqrtf(var + EPSV);
  float* op = out_sph + (size_t)n * SPHD;
  op[l]      = d0 * sc * o3_w[l]      + o3_b[l];
  op[l + 64] = d1 * sc * o3_w[l + 64] + o3_b[l + 64];

  float v0 = xp[128 + l], v1 = xp[128 + 64 + l], v2 = xp[128 + 128 + l];
  float nv = wave_sum(v0 * v0 + v1 * v1 + v2 * v2) * (1.f / 192.f);
  sc = rsqrtf(nv + EPSV);
  op[128 + l]       = v0 * sc * o3_w[MUL0 + (l) / 3];
  op[128 + 64 + l]  = v1 * sc * o3_w[MUL0 + (l + 64) / 3];
  op[128 + 128 + l] = v2 * sc * o3_w[MUL0 + (l + 128) / 3];

  float t0 = xp[320 + l], t1 = xp[320 + 64 + l];
  float t2 = (l < 32) ? xp[320 + 128 + l] : 0.f;
  float nt = wave_sum(t0 * t0 + t1 * t1 + t2 * t2) * (1.f / 160.f);
  sc = rsqrtf(nt + EPSV);
  op[320 + l]      = t0 * sc * o3_w[MUL0 + MUL1 + (l) / 5];
  op[320 + 64 + l] = t1 * sc * o3_w[MUL0 + MUL1 + (l + 64) / 5];
  if (l < 32) op[320 + 128 + l] = t2 * sc * o3_w[MUL0 + MUL1 + (l + 128) / 5];
}

// ---------------------------------------------------------------------------
// Pack B (KxN fp32, K=128) into bf16 MFMA-fragment order.
// ---------------------------------------------------------------------------
__global__ void pack_b_kernel(const float* __restrict__ B, unsigned short* __restrict__ Bp,
                              int N, int NT) {
  int id = blockIdx.x * 256 + threadIdx.x;
  int total = 4 * NT * 64;
  if (id >= total) return;
  int lane = id & 63;
  int tmp = id >> 6;
  int nt = tmp % NT, ks = tmp / NT;
  int n = nt * 16 + (lane & 15);
  int kb = ks * 32 + (lane >> 4) * 8;
  unsigned short* o = Bp + (size_t)id * 8;
  #pragma unroll
  for (int j = 0; j < 8; ++j)
    o[j] = (n < N) ? f2bf(B[(size_t)(kb + j) * N + n]) : (unsigned short)0;
}

// Pack Wrbf [20][352] into MFMA B-fragment order for K=32 (k=20..31 zero),
// NT = 22 col-tiles.
__global__ void pack_bw_kernel(const float* __restrict__ Wrbf, unsigned short* __restrict__ Bpw) {
  int id = blockIdx.x * 256 + threadIdx.x;
  if (id >= 22 * 64) return;
  int lane = id & 63, nt = id >> 6;
  int n = nt * 16 + (lane & 15);
  int kb = (lane >> 4) * 8;
  unsigned short* o = Bpw + (size_t)id * 8;
  #pragma unroll
  for (int j = 0; j < 8; ++j) {
    int k = kb + j;
    o[j] = (k < NBASIS) ? f2bf(Wrbf[(size_t)k * HID + n]) : (unsigned short)0;
  }
}

// ---------------------------------------------------------------------------
// bf16 MFMA GEMM: C = act(A @ B + bias), K = 128 fixed.
// PERM: store columns permuted for the gather's paired-load layout:
//   col <  96       -> slot 2*col       (pairs with col+256)
//   96 <= col < 256 -> slot col + 96
//   col >= 256      -> slot 2*(col-256)+1
// ---------------------------------------------------------------------------
template <bool A_BF16, bool SILU, bool OUT_BF16, bool PERM>
__global__ __launch_bounds__(256) void mfma_gemm_kernel(
    const void* __restrict__ Ap, const unsigned short* __restrict__ Bp,
    const float* __restrict__ bias, void* __restrict__ Cp,
    int M, int N, int NT) {
  const int lane = threadIdx.x & 63;
  const int wave = threadIdx.x >> 6;
  const int bm = blockIdx.x * 64 + wave * 16;
  const int bn = blockIdx.y * 64;
  const int q = lane >> 4;
  const int arow = min(bm + (lane & 15), M - 1);  // clamp: OOB rows give garbage, stores guarded

  f32x4 acc[4] = {};
  #pragma unroll
  for (int ks = 0; ks < 4; ++ks) {
    const int k = ks * 32 + q * 8;
    bf16x8 a;
    if (A_BF16) {
      a = *(const bf16x8*)((const unsigned short*)Ap + (size_t)arow * 128 + k);
    } else {
      const float* ap = (const float*)Ap + (size_t)arow * 128 + k;
      float4 f0 = *(const float4*)ap;
      float4 f1 = *(const float4*)(ap + 4);
      union { bf16x8 v; unsigned short s[8]; } cv;
      cv.s[0] = f2bf(f0.x); cv.s[1] = f2bf(f0.y); cv.s[2] = f2bf(f0.z); cv.s[3] = f2bf(f0.w);
      cv.s[4] = f2bf(f1.x); cv.s[5] = f2bf(f1.y); cv.s[6] = f2bf(f1.z); cv.s[7] = f2bf(f1.w);
      a = cv.v;
    }
    #pragma unroll
    for (int nt = 0; nt < 4; ++nt) {
      bf16x8 b = *(const bf16x8*)(Bp + ((size_t)(ks * NT + blockIdx.y * 4 + nt) * 64 + lane) * 8);
      acc[nt] = __builtin_amdgcn_mfma_f32_16x16x32_bf16(a, b, acc[nt], 0, 0, 0);
    }
  }
  #pragma unroll
  for (int nt = 0; nt < 4; ++nt) {
    int col = bn + nt * 16 + (lane & 15);
    if (col >= N) continue;
    float bz = bias[col];
    int pcol = col;
    if (PERM) pcol = (col < 96) ? (2 * col) : ((col < 256) ? (col + 96) : (2 * (col - 256) + 1));
    #pragma unroll
    for (int i = 0; i < 4; ++i) {
      int r = bm + q * 4 + i;
      if (r >= M) continue;
      float v = acc[nt][i] + bz;
      if (SILU) v = v / (1.f + __expf(-v));
      if (OUT_BF16) ((unsigned short*)Cp)[(size_t)r * N + pcol] = f2bf(v);
      else          ((float*)Cp)[(size_t)r * N + pcol] = v;
    }
  }
}

// ---------------------------------------------------------------------------
// CSR build: histogram, hierarchical exclusive scan (3 kernels), fused fill.
// ---------------------------------------------------------------------------
__global__ void hist_kernel(const int* __restrict__ ei, int* __restrict__ deg, int n_edges) {
  int e = blockIdx.x * blockDim.x + threadIdx.x;
  if (e < n_edges) atomicAdd(&deg[ei[e]], 1);
}

__global__ __launch_bounds__(1024) void scan_part_kernel(
    const int* __restrict__ deg, int* __restrict__ offs, int* __restrict__ bsum, int n) {
  __shared__ int wsum[16];
  const int tid = threadIdx.x, lane = tid & 63, wid = tid >> 6;
  int i = blockIdx.x * 1024 + tid;
  int v = (i < n) ? deg[i] : 0;
  int s = v;
  #pragma unroll
  for (int o = 1; o < 64; o <<= 1) {
    int t = __shfl_up(s, o, 64);
    if (lane >= o) s += t;
  }
  if (lane == 63) wsum[wid] = s;
  __syncthreads();
  if (wid == 0) {
    int ws = (lane < 16) ? wsum[lane] : 0;
    #pragma unroll
    for (int o = 1; o < 16; o <<= 1) {
      int t = __shfl_up(ws, o, 64);
      if (lane >= o) ws += t;
    }
    if (lane < 16) wsum[lane] = ws;
  }
  __syncthreads();
  int excl = ((wid == 0) ? 0 : wsum[wid - 1]) + s - v;
  if (i < n) offs[i] = excl;
  if (tid == 1023) bsum[blockIdx.x] = wsum[15];
}

__global__ __launch_bounds__(64) void scan_tops_kernel(
    const int* __restrict__ bsum, int* __restrict__ bbase, int* __restrict__ offs,
    int nb, int n) {
  const int lane = threadIdx.x;
  int v = (lane < nb) ? bsum[lane] : 0;
  int s = v;
  #pragma unroll
  for (int o = 1; o < 64; o <<= 1) {
    int t = __shfl_up(s, o, 64);
    if (lane >= o) s += t;
  }
  if (lane < nb) bbase[lane] = s - v;
  if (lane == 63) offs[n] = s;  // grand total
}

__global__ __launch_bounds__(1024) void scan_add_kernel(
    int* __restrict__ offs, const int* __restrict__ bbase, int n) {
  int i = blockIdx.x * 1024 + threadIdx.x;
  if (i < n) offs[i] += bbase[blockIdx.x];
}

// Fused fill + pre-gather: place each edge's rbf/vec/src directly at its CSR
// slot. Reads coalesced (edge-order), writes scattered.
__global__ void fill_kernel(const int* __restrict__ ei, const int* __restrict__ offs,
                            int* __restrict__ cursor, const int* __restrict__ edge_src,
                            const float* __restrict__ rbf, const float* __restrict__ vec,
                            float* __restrict__ rbf_s, float* __restrict__ vec_s,
                            int* __restrict__ src_s, int n_edges) {
  int e = blockIdx.x * blockDim.x + threadIdx.x;
  if (e < n_edges) {
    int d = ei[e];
    int p = atomicAdd(&cursor[d], 1);
    int ii = offs[d] + p;
    src_s[ii] = edge_src[e];
    const float4* rp = (const float4*)(rbf + (size_t)e * NBASIS);
    float4* op = (float4*)(rbf_s + (size_t)ii * NBASIS);
    op[0] = rp[0]; op[1] = rp[1]; op[2] = rp[2]; op[3] = rp[3]; op[4] = rp[4];
    vec_s[(size_t)ii * 3]     = vec[(size_t)e * 3];
    vec_s[(size_t)ii * 3 + 1] = vec[(size_t)e * 3 + 1];
    vec_s[(size_t)ii * 3 + 2] = vec[(size_t)e * 3 + 2];
  }
}

// ---------------------------------------------------------------------------
// Gather kernel v9: single-barrier chunk, MFMA A-frags straight from global,
// depth-4 so chase. Changes vs R7 (272us, best):
//  - rbf_l LDS staging deleted: the MFMA A-fragment reads rbf_s directly
//    (same fp32 values -> bit-identical fw). One fewer stage pass.
//  - src_l deleted: src_s read directly (block-uniform, L1-hot).
//  - ONE barrier per chunk (sh_l write + fw_l write -> barrier -> accumulate).
//  - LDS 29.2 -> 26.4 KB: 6 blocks/CU (was 4). More latency overlap.
//  - accumulate depth-4 (clean main/pair/single tails, no guards; R8's
//    guarded depth-8 regressed and is reverted).
// Accumulation order unchanged -> bit-identical to R7.
// ---------------------------------------------------------------------------
#define NPB 3
#define CHUNK 32
#define FWPAD 36   // LDS row pad: 72B stride => 8B-aligned b64 writes, spread banks
#define S3f  1.7320508075688772f
#define S15f 3.872983346207417f
#define S5f  2.2360679774997896f

__device__ __forceinline__ void so_load(const unsigned short* __restrict__ so,
                                        int src, int t, bool hasB,
                                        float& sA, float& sB) {
  const unsigned short* p = so + (size_t)src * HID;
  if (hasB) {
    unsigned int u = *(const unsigned int*)(p + 2 * t);
    sA = __uint_as_float(u << 16);
    sB = __uint_as_float(u & 0xffff0000u);
  } else {
    sA = bf2f(p[t + 96]);
    sB = 0.f;
  }
}

__global__ __launch_bounds__(256) void gather_kernel(
    const float* __restrict__ rbf_s, const float* __restrict__ vec_s,
    const unsigned short* __restrict__ Bpw, const unsigned short* __restrict__ so,
    const int* __restrict__ src_s, const int* __restrict__ offs,
    float* __restrict__ out_scal, float* __restrict__ out_sph, int n_nodes) {
  __shared__ float sh_l[CHUNK * 8];              // 1024 B
  __shared__ unsigned short fw_l[HID * FWPAD];   // 25344 B, [col][edge] transposed

  const int t = threadIdx.x;
  const int lane = t & 63, w = t >> 6, q = lane >> 4;
  const bool hasB = (t < 96);

  const int n0 = blockIdx.x * NPB;
  if (n0 >= n_nodes) return;
  const int nE = min(n0 + NPB, n_nodes);
  const int E0 = offs[n0], E1 = offs[nE];

  int eb0[NPB], eb1[NPB];
  #pragma unroll
  for (int i = 0; i < NPB; ++i) {
    int nd = n0 + i;
    eb0[i] = (nd < n_nodes) ? offs[nd] : E1;
    eb1[i] = (nd < n_nodes) ? offs[nd + 1] : E1;
  }

  float a0[NPB] = {}, a1[NPB] = {}, a2[NPB] = {}, a3[NPB] = {}, a4[NPB] = {}, aB[NPB] = {};

  for (int C0 = E0; C0 < E1; C0 += CHUNK) {
    const int C1 = min(C0 + CHUNK, E1);
    const int ns = C1 - C0;

    // ---- sh staging (threads t<ns; no barrier needed before MFMA phase) ----
    if (t < ns) {
      const int ii = C0 + t;
      float vx = vec_s[3 * (size_t)ii], vy = vec_s[3 * (size_t)ii + 1], vz = vec_s[3 * (size_t)ii + 2];
      float rn = rsqrtf(vx * vx + vy * vy + vz * vz);
      float x = vx * rn, y = vy * rn, z = vz * rn;
      float* sp = &sh_l[t * 8];
      sp[0] = S3f * x; sp[1] = S3f * y; sp[2] = S3f * z;
      sp[3] = S15f * x * z;
      sp[4] = S15f * x * y;
      sp[5] = S5f * (y * y - 0.5f * (x * x + z * z));
      sp[6] = S15f * y * z;
      sp[7] = 0.5f * S15f * (z * z - x * x);
    }

    // ---- MFMA: fw[0..31][0..351] = rbf_chunk @ Wrbf, A-frags from GLOBAL ----
    // Rows >= ns produce garbage fw never read by the accum phase (reads stay
    // inside d_ws).
    {
      const int et = w >> 1;
      const int ntb = (w & 1) * 11;
      const int mrow = et * 16 + (lane & 15);
      const float* ar = rbf_s + (size_t)(C0 + mrow) * NBASIS;
      f32x4 lo = {}, hi = {};
      if (q < 2) {
        lo = *(const f32x4*)(ar + q * 8);
        hi = *(const f32x4*)(ar + q * 8 + 4);
      } else if (q == 2) {
        lo = *(const f32x4*)(ar + 16);  // k=16..19; k>=20 zero-padded
      }
      union { bf16x8 v; unsigned int u[4]; } af;
      af.u[0] = cvt_pk_bf16(lo[0], lo[1]);
      af.u[1] = cvt_pk_bf16(lo[2], lo[3]);
      af.u[2] = cvt_pk_bf16(hi[0], hi[1]);
      af.u[3] = cvt_pk_bf16(hi[2], hi[3]);
      #pragma unroll
      for (int j = 0; j < 11; ++j) {
        const int nt = ntb + j;
        bf16x8 b = *(const bf16x8*)(Bpw + (size_t)(nt * 64 + lane) * 8);
        f32x4 acc = {};
        acc = __builtin_amdgcn_mfma_f32_16x16x32_bf16(af.v, b, acc, 0, 0, 0);
        const int col = nt * 16 + (lane & 15);
        uint2 pk;
        pk.x = cvt_pk_bf16(acc[0], acc[1]);
        pk.y = cvt_pk_bf16(acc[2], acc[3]);
        *(uint2*)&fw_l[col * FWPAD + et * 16 + q * 4] = pk;
      }
    }
    __syncthreads();   // single barrier: covers sh_l and fw_l

    // ---- accumulate: depth-4 main body + pair + single tails ----
    auto edge = [&](int il, float sA, float sB, int nn) {
      float fwA = bf2f(fw_l[t * FWPAD + il]);
      float fA = sA * fwA;
      if (t < 128) {
        a0[nn] += fA;
      } else if (t < 224) {
        const float* sp = &sh_l[il * 8];
        if (t < 192) {
          a0[nn] += fA * sp[0]; a1[nn] += fA * sp[1]; a2[nn] += fA * sp[2];
        } else {
          a0[nn] += fA * sp[3]; a1[nn] += fA * sp[4]; a2[nn] += fA * sp[5];
          a3[nn] += fA * sp[6]; a4[nn] += fA * sp[7];
        }
      } else {
        a0[nn] += fA;
      }
      if (hasB) {
        float fwB = bf2f(fw_l[(256 + t) * FWPAD + il]);
        aB[nn] += sB * fwB;
      }
    };

    #pragma unroll
    for (int nn = 0; nn < NPB; ++nn) {
      const int lo = max(eb0[nn], C0);
      const int hi = min(eb1[nn], C1);
      int ii = lo;
      for (; ii + 4 <= hi; ii += 4) {
        const int s0 = src_s[ii], s1 = src_s[ii + 1], s2 = src_s[ii + 2], s3 = src_s[ii + 3];
        float sA0, sB0, sA1, sB1, sA2, sB2, sA3, sB3;
        so_load(so, s0, t, hasB, sA0, sB0);
        so_load(so, s1, t, hasB, sA1, sB1);
        so_load(so, s2, t, hasB, sA2, sB2);
        so_load(so, s3, t, hasB, sA3, sB3);
        edge(ii - C0,     sA0, sB0, nn);
        edge(ii - C0 + 1, sA1, sB1, nn);
        edge(ii - C0 + 2, sA2, sB2, nn);
        edge(ii - C0 + 3, sA3, sB3, nn);
      }
      for (; ii + 2 <= hi; ii += 2) {
        const int s0 = src_s[ii], s1 = src_s[ii + 1];
        float sA0, sB0, sA1, sB1;
        so_load(so, s0, t, hasB, sA0, sB0);
        so_load(so, s1, t, hasB, sA1, sB1);
        edge(ii - C0,     sA0, sB0, nn);
        edge(ii - C0 + 1, sA1, sB1, nn);
      }
      if (ii < hi) {
        const int s0 = src_s[ii];
        float sA0, sB0;
        so_load(so, s0, t, hasB, sA0, sB0);
        edge(ii - C0, sA0, sB0, nn);
      }
    }
    __syncthreads();   // protect sh_l/fw_l before next chunk overwrites
  }

  // ---- flush (base values already in d_out from node_norm) ----
  #pragma unroll
  for (int nn = 0; nn < NPB; ++nn) {
    const int node = n0 + nn;
    if (node >= n_nodes) break;
    float* sph = out_sph + (size_t)node * SPHD;
    float* scl = out_scal + (size_t)node * N_DIM;
    if (t < 128) {
      sph[t] += a0[nn];
    } else if (t < 192) {
      float* p = sph + 128 + 3 * (t - 128);
      p[0] += a0[nn]; p[1] += a1[nn]; p[2] += a2[nn];
    } else if (t < 224) {
      float* p = sph + 320 + 5 * (t - 192);
      p[0] += a0[nn]; p[1] += a1[nn]; p[2] += a2[nn]; p[3] += a3[nn]; p[4] += a4[nn];
    } else {
      scl[t - 224] += a0[nn];
    }
    if (hasB) scl[t + 32] += aB[nn];
  }
}

// ---------------------------------------------------------------------------
extern "C" void kernel_launch(void* const* d_in, const int* in_sizes, int n_in,
                              void* d_out, int out_size, void* d_ws, size_t ws_size,
                              hipStream_t stream) {
  const float* x_scalar = (const float*)d_in[0];
  const float* x_sph    = (const float*)d_in[1];
  const float* rbf      = (const float*)d_in[2];
  const float* vec      = (const float*)d_in[3];
  const float* W1       = (const float*)d_in[4];
  const float* b1       = (const float*)d_in[5];
  const float* W2       = (const float*)d_in[6];
  const float* b2       = (const float*)d_in[7];
  const float* Wrbf     = (const float*)d_in[8];
  const float* ln_g     = (const float*)d_in[9];
  const float* ln_b     = (const float*)d_in[10];
  const float* o3_w     = (const float*)d_in[11];
  const float* o3_b     = (const float*)d_in[12];
  const int*   edge_idx = (const int*)d_in[13];

  const int n_nodes = in_sizes[0] / N_DIM;   // 50000
  const int n_edges = in_sizes[2] / NBASIS;  // 400000

  float* out_scal = (float*)d_out;                       // [n_nodes,128]
  float* out_sph  = out_scal + (size_t)n_nodes * N_DIM;  // [n_nodes,480]

  // workspace layout (16B alignment preserved chunk to chunk)
  float* rbf_s = (float*)d_ws;                                // [n_edges,20] CSR order
  float* vec_s = rbf_s + (size_t)n_edges * NBASIS;            // [n_edges,3]  CSR order
  int*   src_s = (int*)(vec_s + (size_t)n_edges * 3);         // [n_edges]    CSR order
  unsigned short* so_bf = (unsigned short*)(src_s + n_edges); // [n_nodes,352] bf16 permuted
  unsigned short* h_bf  = so_bf + (size_t)n_nodes * HID;      // [n_nodes,128] bf16
  unsigned short* bp1   = h_bf + (size_t)n_nodes * N_DIM;     // 16384 ush
  unsigned short* bp2   = bp1 + 16384;                        // 49152 ush
  unsigned short* bpw   = bp2 + 49152;                        // 22*64*8 = 11264 ush
  int* deg    = (int*)(bpw + 11264);
  int* cursor = deg + n_nodes;
  int* offs   = cursor + n_nodes;       // [n_nodes+1]
  int* bsum   = offs + n_nodes + 1;     // [64]
  int* bbase  = bsum + 64;              // [64]

  const int* edge_dst = edge_idx;
  const int* edge_src = edge_idx + n_edges;

  // 1) node norms -> d_out (scatter base)
  node_norm_kernel<<<(n_nodes + 3) / 4, 256, 0, stream>>>(
      x_scalar, x_sph, ln_g, ln_b, o3_w, o3_b, out_scal, out_sph, n_nodes);

  // 2) pack W1/W2 (MFMA fragment order) + Wrbf (K=32 fragment order)
  pack_b_kernel<<<8, 256, 0, stream>>>(W1, bp1, N_DIM, 8);
  pack_b_kernel<<<24, 256, 0, stream>>>(W2, bp2, HID, 24);
  pack_bw_kernel<<<6, 256, 0, stream>>>(Wrbf, bpw);

  // 3) h = silu(scalar_in @ W1 + b1)  (A fp32, out bf16)
  {
    dim3 g((n_nodes + 63) / 64, 2);
    mfma_gemm_kernel<false, true, true, false><<<g, 256, 0, stream>>>(
        out_scal, bp1, b1, h_bf, n_nodes, N_DIM, 8);
  }
  // 4) scalar_out = h @ W2 + b2  (A bf16, out bf16 PERMUTED for paired loads)
  {
    dim3 g((n_nodes + 63) / 64, 6);
    mfma_gemm_kernel<true, false, true, true><<<g, 256, 0, stream>>>(
        h_bf, bp2, b2, so_bf, n_nodes, HID, 24);
  }

  // 5) CSR build (fill fused with pre-gather: streams land in CSR slots)
  hipMemsetAsync(deg, 0, sizeof(int) * 2 * n_nodes, stream);  // deg + cursor
  hist_kernel<<<(n_edges + 255) / 256, 256, 0, stream>>>(edge_dst, deg, n_edges);
  const int nb = (n_nodes + 1023) / 1024;  // 49
  scan_part_kernel<<<nb, 1024, 0, stream>>>(deg, offs, bsum, n_nodes);
  scan_tops_kernel<<<1, 64, 0, stream>>>(bsum, bbase, offs, nb, n_nodes);
  scan_add_kernel<<<nb, 1024, 0, stream>>>(offs, bbase, n_nodes);
  fill_kernel<<<(n_edges + 255) / 256, 256, 0, stream>>>(
      edge_dst, offs, cursor, edge_src, rbf, vec, rbf_s, vec_s, src_s, n_edges);

  // 6) gather: single-barrier chunks, MFMA fw, depth-4 chase
  gather_kernel<<<(n_nodes + NPB - 1) / NPB, 256, 0, stream>>>(
      rbf_s, vec_s, bpw, so_bf, src_s, offs, out_scal, out_sph, n_nodes);
}